// Round 1
// baseline (871.899 us; speedup 1.0000x reference)
//
#include <hip/hip_runtime.h>
#include <math.h>

#define NEG_SLOPE 0.2f
#define DMODEL 128

// ---- float <-> order-preserving uint encoding (for atomicMax on floats) ----
__device__ __forceinline__ unsigned enc_f(float f) {
    unsigned u = __float_as_uint(f);
    return (u & 0x80000000u) ? ~u : (u | 0x80000000u);
}
__device__ __forceinline__ float dec_f(unsigned u) {
    unsigned b = (u & 0x80000000u) ? (u & 0x7fffffffu) : ~u;
    return __uint_as_float(b);
}
__device__ __forceinline__ float leaky(float x) { return x >= 0.f ? x : NEG_SLOPE * x; }

// ---- K1: h = x@W (8 nodes/block for W L2-reuse) + per-node attention halves ----
__global__ __launch_bounds__(128) void k1_gemm_att(
    const float* __restrict__ x, const float* __restrict__ W,
    const float* __restrict__ att_src, const float* __restrict__ att_dst,
    float* __restrict__ h, float* __restrict__ a_src, float* __restrict__ a_dst,
    unsigned* __restrict__ m_enc, float* __restrict__ denom, int N)
{
    __shared__ float xs[8][DMODEL];
    const int t = threadIdx.x;
    const int n0 = blockIdx.x * 8;
    #pragma unroll
    for (int i = 0; i < 8; i++) {
        int n = n0 + i;
        xs[i][t] = (n < N) ? x[(size_t)n * DMODEL + t] : 0.f;
    }
    __syncthreads();
    float acc[8] = {0.f, 0.f, 0.f, 0.f, 0.f, 0.f, 0.f, 0.f};
    for (int k = 0; k < DMODEL; k++) {
        float wk = W[k * DMODEL + t];
        #pragma unroll
        for (int i = 0; i < 8; i++) acc[i] += xs[i][k] * wk;
    }
    const float as = att_src[t];   // att_src flat [H*32] == indexed by t
    const float ad = att_dst[t];
    const int head = t >> 5, d = t & 31;
    #pragma unroll
    for (int i = 0; i < 8; i++) {
        int n = n0 + i;
        if (n < N) {
            h[(size_t)n * DMODEL + t] = acc[i];
            float vs = acc[i] * as;
            float vd = acc[i] * ad;
            #pragma unroll
            for (int off = 16; off > 0; off >>= 1) {
                vs += __shfl_xor(vs, off, 32);
                vd += __shfl_xor(vd, off, 32);
            }
            if (d == 0) {
                a_src[n * 4 + head] = vs;
                a_dst[n * 4 + head] = vd;
                // seed segment-max with the self-loop logit; zero the denom
                m_enc[n * 4 + head] = enc_f(leaky(vs + vd));
                denom[n * 4 + head] = 0.f;
            }
        }
    }
}

// ---- K2: per-edge segment max (atomicMax on encoded floats) ----
__global__ __launch_bounds__(256) void k2_edge_max(
    const int* __restrict__ srcs, const int* __restrict__ dsts,
    const float* __restrict__ a_src, const float* __restrict__ a_dst,
    unsigned* __restrict__ m_enc, int E)
{
    int e = blockIdx.x * 256 + threadIdx.x;
    if (e >= E) return;
    int s = srcs[e], d = dsts[e];
    float4 as = *(const float4*)(a_src + (size_t)s * 4);
    float4 ad = *(const float4*)(a_dst + (size_t)d * 4);
    unsigned* mp = m_enc + (size_t)d * 4;
    atomicMax(mp + 0, enc_f(leaky(as.x + ad.x)));
    atomicMax(mp + 1, enc_f(leaky(as.y + ad.y)));
    atomicMax(mp + 2, enc_f(leaky(as.z + ad.z)));
    atomicMax(mp + 3, enc_f(leaky(as.w + ad.w)));
}

// ---- K3: per-edge exp(logit - m), store ealpha, atomicAdd denom ----
__global__ __launch_bounds__(256) void k3_edge_exp(
    const int* __restrict__ srcs, const int* __restrict__ dsts,
    const float* __restrict__ a_src, const float* __restrict__ a_dst,
    const unsigned* __restrict__ m_enc, float* __restrict__ denom,
    float* __restrict__ ealpha, int E)
{
    int e = blockIdx.x * 256 + threadIdx.x;
    if (e >= E) return;
    int s = srcs[e], d = dsts[e];
    float4 as = *(const float4*)(a_src + (size_t)s * 4);
    float4 ad = *(const float4*)(a_dst + (size_t)d * 4);
    uint4  mu = *(const uint4*)(m_enc + (size_t)d * 4);
    float e0 = __expf(leaky(as.x + ad.x) - dec_f(mu.x));
    float e1 = __expf(leaky(as.y + ad.y) - dec_f(mu.y));
    float e2 = __expf(leaky(as.z + ad.z) - dec_f(mu.z));
    float e3 = __expf(leaky(as.w + ad.w) - dec_f(mu.w));
    *(float4*)(ealpha + (size_t)e * 4) = make_float4(e0, e1, e2, e3);
    float* dp = denom + (size_t)d * 4;
    unsafeAtomicAdd(dp + 0, e0);
    unsafeAtomicAdd(dp + 1, e1);
    unsafeAtomicAdd(dp + 2, e2);
    unsafeAtomicAdd(dp + 3, e3);
}

// ---- K4: init out with self-loop contribution; add self term to denom ----
__global__ __launch_bounds__(256) void k4_self_init(
    const float* __restrict__ h, const float* __restrict__ a_src,
    const float* __restrict__ a_dst, const unsigned* __restrict__ m_enc,
    float* __restrict__ denom, float* __restrict__ out, int N)
{
    int idx = blockIdx.x * 256 + threadIdx.x;
    if (idx >= N * DMODEL) return;
    int n = idx >> 7, t = idx & 127, head = t >> 5;
    float m  = dec_f(m_enc[n * 4 + head]);
    float L  = leaky(a_src[n * 4 + head] + a_dst[n * 4 + head]);
    float es = __expf(L - m);
    out[idx] = h[idx] * es;
    if (t < 4) {  // one thread per (n, head): non-atomic add of self term
        float Lh = leaky(a_src[n * 4 + t] + a_dst[n * 4 + t]);
        denom[n * 4 + t] += __expf(Lh - dec_f(m_enc[n * 4 + t]));
    }
}

// ---- K5: one wave per edge — gather h[src], scale, atomic scatter to out[dst] ----
__global__ __launch_bounds__(256) void k5_scatter(
    const int* __restrict__ srcs, const int* __restrict__ dsts,
    const float* __restrict__ h, const float* __restrict__ ealpha,
    float* __restrict__ out, int E)
{
    int w = (blockIdx.x * 256 + threadIdx.x) >> 6;   // wave id = edge id
    if (w >= E) return;
    int lane = threadIdx.x & 63;
    int s = srcs[w], d = dsts[w];
    float4 ea = *(const float4*)(ealpha + (size_t)w * 4);  // broadcast load
    float a = ((const float*)&ea)[lane >> 4];              // head = (2*lane)>>5 = lane>>4
    float2 hv = *(const float2*)(h + (size_t)s * DMODEL + lane * 2);
    float* op = out + (size_t)d * DMODEL + lane * 2;
    unsafeAtomicAdd(op + 0, hv.x * a);
    unsafeAtomicAdd(op + 1, hv.y * a);
}

// ---- K6: out = tanh(acc/denom + bias) ----
__global__ __launch_bounds__(256) void k6_final(
    const float* __restrict__ denom, const float* __restrict__ bias,
    float* __restrict__ out, int N)
{
    int idx = blockIdx.x * 256 + threadIdx.x;
    if (idx >= N * DMODEL) return;
    int n = idx >> 7, t = idx & 127, head = t >> 5;
    float v = out[idx] / denom[n * 4 + head] + bias[t];
    out[idx] = tanhf(v);
}

extern "C" void kernel_launch(void* const* d_in, const int* in_sizes, int n_in,
                              void* d_out, int out_size, void* d_ws, size_t ws_size,
                              hipStream_t stream) {
    const float* x       = (const float*)d_in[0];
    const int*   edges   = (const int*)d_in[1];   // [2,E] flattened: row0=src, row1=dst
    const float* W       = (const float*)d_in[2];
    const float* att_src = (const float*)d_in[3];
    const float* att_dst = (const float*)d_in[4];
    const float* bias    = (const float*)d_in[5];
    float* out = (float*)d_out;

    const int N = in_sizes[0] / DMODEL;   // 50000
    const int E = in_sizes[1] / 2;        // 600000
    const int* srcs = edges;
    const int* dsts = edges + E;

    // workspace layout (floats): h[N*128] | a_src[N*4] | a_dst[N*4] | m_enc[N*4] | denom[N*4] | ealpha[E*4]
    float* ws      = (float*)d_ws;
    float* h       = ws;
    float* a_src   = h + (size_t)N * DMODEL;
    float* a_dst   = a_src + (size_t)N * 4;
    unsigned* m_enc = (unsigned*)(a_dst + (size_t)N * 4);
    float* denom   = (float*)m_enc + (size_t)N * 4;
    float* ealpha  = denom + (size_t)N * 4;

    k1_gemm_att<<<(N + 7) / 8, 128, 0, stream>>>(x, W, att_src, att_dst,
                                                 h, a_src, a_dst, m_enc, denom, N);
    k2_edge_max<<<(E + 255) / 256, 256, 0, stream>>>(srcs, dsts, a_src, a_dst, m_enc, E);
    k3_edge_exp<<<(E + 255) / 256, 256, 0, stream>>>(srcs, dsts, a_src, a_dst, m_enc,
                                                     denom, ealpha, E);
    k4_self_init<<<(N * DMODEL + 255) / 256, 256, 0, stream>>>(h, a_src, a_dst, m_enc,
                                                               denom, out, N);
    k5_scatter<<<(E * 64 + 255) / 256, 256, 0, stream>>>(srcs, dsts, h, ealpha, out, E);
    k6_final<<<(N * DMODEL + 255) / 256, 256, 0, stream>>>(denom, bias, out, N);
}

// Round 2
// 309.649 us; speedup vs baseline: 2.8158x; 2.8158x over previous
//
#include <hip/hip_runtime.h>
#include <math.h>

#define NEG_SLOPE 0.2f
#define DMODEL 128

__device__ __forceinline__ float leaky(float x) { return x >= 0.f ? x : NEG_SLOPE * x; }

// ---- K1: h = x@W (8 nodes/block for W reuse) + per-node attention halves ----
__global__ __launch_bounds__(128) void k1_gemm_att(
    const float* __restrict__ x, const float* __restrict__ W,
    const float* __restrict__ att_src, const float* __restrict__ att_dst,
    float* __restrict__ h, float* __restrict__ a_src, float* __restrict__ a_dst, int N)
{
    __shared__ float xs[8][DMODEL];
    const int t = threadIdx.x;
    const int n0 = blockIdx.x * 8;
    #pragma unroll
    for (int i = 0; i < 8; i++) {
        int n = n0 + i;
        xs[i][t] = (n < N) ? x[(size_t)n * DMODEL + t] : 0.f;
    }
    __syncthreads();
    float acc[8] = {0.f, 0.f, 0.f, 0.f, 0.f, 0.f, 0.f, 0.f};
    for (int k = 0; k < DMODEL; k++) {
        float wk = W[k * DMODEL + t];
        #pragma unroll
        for (int i = 0; i < 8; i++) acc[i] += xs[i][k] * wk;
    }
    const float as = att_src[t];
    const float ad = att_dst[t];
    const int head = t >> 5, d = t & 31;
    #pragma unroll
    for (int i = 0; i < 8; i++) {
        int n = n0 + i;
        if (n < N) {
            h[(size_t)n * DMODEL + t] = acc[i];
            float vs = acc[i] * as;
            float vd = acc[i] * ad;
            #pragma unroll
            for (int off = 16; off > 0; off >>= 1) {
                vs += __shfl_xor(vs, off, 32);
                vd += __shfl_xor(vd, off, 32);
            }
            if (d == 0) {
                a_src[n * 4 + head] = vs;
                a_dst[n * 4 + head] = vd;
            }
        }
    }
}

// ---- CSR build: zero degrees ----
__global__ __launch_bounds__(256) void kz_zero(int* __restrict__ deg, int N) {
    int i = blockIdx.x * 256 + threadIdx.x;
    if (i < N) deg[i] = 0;
}

// ---- CSR build: count in-degree per destination ----
__global__ __launch_bounds__(256) void kc_count(const int* __restrict__ dsts,
                                                int* __restrict__ deg, int E) {
    int e = blockIdx.x * 256 + threadIdx.x;
    if (e < E) atomicAdd(&deg[dsts[e]], 1);
}

// ---- CSR build: single-block chunked exclusive scan ----
__global__ __launch_bounds__(1024) void ks_scan(const int* __restrict__ deg,
                                                int* __restrict__ offsets,
                                                int* __restrict__ cursor, int N) {
    __shared__ int wsum[16];
    __shared__ int running_s;
    const int t = threadIdx.x;
    const int lane = t & 63, wv = t >> 6;
    if (t == 0) running_s = 0;
    __syncthreads();
    for (int base = 0; base < N; base += 1024) {
        int i = base + t;
        int v = (i < N) ? deg[i] : 0;
        int x = v;  // inclusive scan within wave
        #pragma unroll
        for (int off = 1; off < 64; off <<= 1) {
            int y = __shfl_up(x, off, 64);
            if (lane >= off) x += y;
        }
        if (lane == 63) wsum[wv] = x;
        __syncthreads();
        if (wv == 0 && lane < 16) {
            int s = wsum[lane];
            #pragma unroll
            for (int off = 1; off < 16; off <<= 1) {
                int y = __shfl_up(s, off, 64);
                if (lane >= off) s += y;
            }
            wsum[lane] = s;  // inclusive wave prefix
        }
        __syncthreads();
        int waveoff = (wv > 0) ? wsum[wv - 1] : 0;
        int incl = x + waveoff;
        int excl = incl - v;
        int run = running_s;
        if (i < N) { int o = run + excl; offsets[i] = o; cursor[i] = o; }
        __syncthreads();
        if (t == 1023) running_s = run + incl;  // chunk total
        __syncthreads();
    }
    if (t == 0) offsets[N] = running_s;
}

// ---- CSR build: scatter edge srcs into slots ----
__global__ __launch_bounds__(256) void kf_fill(const int* __restrict__ srcs,
                                               const int* __restrict__ dsts,
                                               int* __restrict__ cursor,
                                               int* __restrict__ csr_src, int E) {
    int e = blockIdx.x * 256 + threadIdx.x;
    if (e < E) {
        int pos = atomicAdd(&cursor[dsts[e]], 1);
        csr_src[pos] = srcs[e];
    }
}

// ---- KAGG: one wave per dst node — online-softmax gather + fused epilogue ----
__global__ __launch_bounds__(256) void kagg(
    const int* __restrict__ offsets, const int* __restrict__ csr_src,
    const float* __restrict__ h, const float* __restrict__ a_src,
    const float* __restrict__ a_dst, const float* __restrict__ bias,
    float* __restrict__ out, int N)
{
    int w = (blockIdx.x * 256 + threadIdx.x) >> 6;  // wave id = dst node
    if (w >= N) return;
    const int lane = threadIdx.x & 63;
    const int head = lane >> 4;           // (lane*2)>>5

    const float ad = a_dst[(size_t)w * 4 + head];
    // self-loop init: m = l_self, denom = 1, acc = h[w]
    float m = leaky(a_src[(size_t)w * 4 + head] + ad);
    float denom = 1.f;
    float2 acc = *(const float2*)(h + (size_t)w * DMODEL + lane * 2);

    const int j0 = offsets[w], j1 = offsets[w + 1];
    for (int j = j0; j < j1; j++) {
        int s = csr_src[j];
        float as = a_src[(size_t)s * 4 + head];
        float l = leaky(as + ad);
        float nm = fmaxf(m, l);
        float scale = __expf(m - nm);
        float p = __expf(l - nm);
        float2 hv = *(const float2*)(h + (size_t)s * DMODEL + lane * 2);
        acc.x = acc.x * scale + p * hv.x;
        acc.y = acc.y * scale + p * hv.y;
        denom = denom * scale + p;
        m = nm;
    }
    float2 b = *(const float2*)(bias + lane * 2);
    float inv = 1.f / denom;
    float2 o;
    o.x = tanhf(acc.x * inv + b.x);
    o.y = tanhf(acc.y * inv + b.y);
    *(float2*)(out + (size_t)w * DMODEL + lane * 2) = o;
}

extern "C" void kernel_launch(void* const* d_in, const int* in_sizes, int n_in,
                              void* d_out, int out_size, void* d_ws, size_t ws_size,
                              hipStream_t stream) {
    const float* x       = (const float*)d_in[0];
    const int*   edges   = (const int*)d_in[1];   // [2,E]: row0=src, row1=dst
    const float* W       = (const float*)d_in[2];
    const float* att_src = (const float*)d_in[3];
    const float* att_dst = (const float*)d_in[4];
    const float* bias    = (const float*)d_in[5];
    float* out = (float*)d_out;

    const int N = in_sizes[0] / DMODEL;   // 50000
    const int E = in_sizes[1] / 2;        // 600000
    const int* srcs = edges;
    const int* dsts = edges + E;

    // workspace layout:
    // h[N*128] f32 | a_src[N*4] f32 | a_dst[N*4] f32 | deg[N] i32 |
    // offsets[N+1] i32 | cursor[N] i32 | csr_src[E] i32
    float* h     = (float*)d_ws;
    float* a_src = h + (size_t)N * DMODEL;
    float* a_dst = a_src + (size_t)N * 4;
    int* deg     = (int*)(a_dst + (size_t)N * 4);
    int* offsets = deg + N;
    int* cursor  = offsets + (N + 1);
    int* csr_src = cursor + N;

    k1_gemm_att<<<(N + 7) / 8, 128, 0, stream>>>(x, W, att_src, att_dst,
                                                 h, a_src, a_dst, N);
    kz_zero<<<(N + 255) / 256, 256, 0, stream>>>(deg, N);
    kc_count<<<(E + 255) / 256, 256, 0, stream>>>(dsts, deg, E);
    ks_scan<<<1, 1024, 0, stream>>>(deg, offsets, cursor, N);
    kf_fill<<<(E + 255) / 256, 256, 0, stream>>>(srcs, dsts, cursor, csr_src, E);
    kagg<<<(N * 64 + 255) / 256, 256, 0, stream>>>(offsets, csr_src, h, a_src,
                                                   a_dst, bias, out, N);
}

// Round 3
// 291.232 us; speedup vs baseline: 2.9938x; 1.0632x over previous
//
#include <hip/hip_runtime.h>
#include <hip/hip_bf16.h>
#include <math.h>

#define NEG_SLOPE 0.2f
#define DMODEL 128
#define SCAN_CHUNK 1024

__device__ __forceinline__ float leaky(float x) { return x >= 0.f ? x : NEG_SLOPE * x; }

// ---- K1: h = x@W via scalar-load x (wave-uniform rows) + vector W loads.
// 8 nodes/block, 128 threads. No LDS. h stored bf16; att halves in fp32. ----
__global__ __launch_bounds__(128) void k1_gemm_att(
    const float* __restrict__ x, const float* __restrict__ W,
    const float* __restrict__ att_src, const float* __restrict__ att_dst,
    __hip_bfloat16* __restrict__ h, float* __restrict__ a_src,
    float* __restrict__ a_dst, int N)
{
    const int t = threadIdx.x;
    const int n0 = blockIdx.x * 8;
    float acc[8] = {0.f, 0.f, 0.f, 0.f, 0.f, 0.f, 0.f, 0.f};

    // uniform row pointers (clamped; N % 8 == 0 for this problem anyway)
    const float4* xr[8];
    #pragma unroll
    for (int i = 0; i < 8; i++) {
        int n = n0 + i; if (n >= N) n = N - 1;
        xr[i] = (const float4*)(x + (size_t)n * DMODEL);
    }

    for (int k4 = 0; k4 < DMODEL / 4; k4++) {
        float4 xv[8];
        #pragma unroll
        for (int i = 0; i < 8; i++) xv[i] = xr[i][k4];   // s_load_dwordx4 (uniform)
        #pragma unroll
        for (int j = 0; j < 4; j++) {
            float wk = W[(k4 * 4 + j) * DMODEL + t];     // coalesced vector load
            #pragma unroll
            for (int i = 0; i < 8; i++)
                acc[i] += ((const float*)&xv[i])[j] * wk;
        }
    }

    const float as = att_src[t];
    const float ad = att_dst[t];
    const int head = t >> 5, d = t & 31;
    #pragma unroll
    for (int i = 0; i < 8; i++) {
        int n = n0 + i;
        if (n < N) {
            h[(size_t)n * DMODEL + t] = __float2bfloat16(acc[i]);
            float vs = acc[i] * as;
            float vd = acc[i] * ad;
            #pragma unroll
            for (int off = 16; off > 0; off >>= 1) {
                vs += __shfl_xor(vs, off, 32);
                vd += __shfl_xor(vd, off, 32);
            }
            if (d == 0) {
                a_src[n * 4 + head] = vs;
                a_dst[n * 4 + head] = vd;
            }
        }
    }
}

// ---- CSR build: zero degrees ----
__global__ __launch_bounds__(256) void kz_zero(int* __restrict__ deg, int N) {
    int i = blockIdx.x * 256 + threadIdx.x;
    if (i < N) deg[i] = 0;
}

// ---- CSR build: count in-degree per destination ----
__global__ __launch_bounds__(256) void kc_count(const int* __restrict__ dsts,
                                                int* __restrict__ deg, int E) {
    int e = blockIdx.x * 256 + threadIdx.x;
    if (e < E) atomicAdd(&deg[dsts[e]], 1);
}

// ---- Scan phase 1: per-chunk (1024 elems) sums ----
__global__ __launch_bounds__(256) void ks1_bsum(const int* __restrict__ deg,
                                                int* __restrict__ bsum, int N) {
    const int t = threadIdx.x, lane = t & 63, wv = t >> 6;
    int base = blockIdx.x * SCAN_CHUNK + t * 4;
    int s = 0;
    #pragma unroll
    for (int j = 0; j < 4; j++) { int i = base + j; if (i < N) s += deg[i]; }
    #pragma unroll
    for (int off = 32; off > 0; off >>= 1) s += __shfl_xor(s, off, 64);
    __shared__ int ws[4];
    if (lane == 0) ws[wv] = s;
    __syncthreads();
    if (t == 0) bsum[blockIdx.x] = ws[0] + ws[1] + ws[2] + ws[3];
}

// ---- Scan phase 2: exclusive scan of chunk sums (single wave, looped) ----
__global__ __launch_bounds__(64) void ks2_scan(int* __restrict__ bsum, int nb) {
    const int lane = threadIdx.x;
    int run = 0;
    for (int base = 0; base < nb; base += 64) {
        int i = base + lane;
        int v = (i < nb) ? bsum[i] : 0;
        int xx = v;
        #pragma unroll
        for (int off = 1; off < 64; off <<= 1) {
            int y = __shfl_up(xx, off, 64);
            if (lane >= off) xx += y;
        }
        if (i < nb) bsum[i] = run + xx - v;   // exclusive
        run += __shfl(xx, 63, 64);
    }
}

// ---- Scan phase 3: local exclusive scan + chunk offset -> offsets, cursor ----
__global__ __launch_bounds__(256) void ks3_scan(const int* __restrict__ deg,
                                                const int* __restrict__ bsum,
                                                int* __restrict__ offsets,
                                                int* __restrict__ cursor, int N, int E) {
    const int t = threadIdx.x, lane = t & 63, wv = t >> 6;
    int base = blockIdx.x * SCAN_CHUNK + t * 4;
    int v[4]; int s = 0;
    #pragma unroll
    for (int j = 0; j < 4; j++) { int i = base + j; v[j] = (i < N) ? deg[i] : 0; s += v[j]; }
    int xinc = s;
    #pragma unroll
    for (int off = 1; off < 64; off <<= 1) {
        int y = __shfl_up(xinc, off, 64);
        if (lane >= off) xinc += y;
    }
    __shared__ int ws[4];
    if (lane == 63) ws[wv] = xinc;
    __syncthreads();
    int woff = 0;
    #pragma unroll
    for (int j = 0; j < 4; j++) if (j < wv) woff += ws[j];
    int run = bsum[blockIdx.x] + woff + xinc - s;   // thread-exclusive prefix
    #pragma unroll
    for (int j = 0; j < 4; j++) {
        int i = base + j;
        if (i < N) { offsets[i] = run; cursor[i] = run; }
        run += v[j];
    }
    if (blockIdx.x == 0 && t == 0) offsets[N] = E;
}

// ---- CSR build: scatter edge srcs into slots ----
__global__ __launch_bounds__(256) void kf_fill(const int* __restrict__ srcs,
                                               const int* __restrict__ dsts,
                                               int* __restrict__ cursor,
                                               int* __restrict__ csr_src, int E) {
    int e = blockIdx.x * 256 + threadIdx.x;
    if (e < E) {
        int pos = atomicAdd(&cursor[dsts[e]], 1);
        csr_src[pos] = srcs[e];
    }
}

// ---- KAGG: one wave per dst node — two-pass softmax gather + fused epilogue ----
__global__ __launch_bounds__(256) void kagg(
    const int* __restrict__ offsets, const int* __restrict__ csr_src,
    const __hip_bfloat16* __restrict__ h, const float* __restrict__ a_src,
    const float* __restrict__ a_dst, const float* __restrict__ bias,
    float* __restrict__ out, int N)
{
    int w = (blockIdx.x * 256 + threadIdx.x) >> 6;  // wave id = dst node
    if (w >= N) return;
    const int lane = threadIdx.x & 63;
    const int head = lane >> 4;

    const float ad = a_dst[(size_t)w * 4 + head];
    const float lself = leaky(a_src[(size_t)w * 4 + head] + ad);
    const int j0 = offsets[w], j1 = offsets[w + 1];

    // pass 1: segment max (self-loop included)
    float m = lself;
    for (int j = j0; j < j1; j++) {
        int s = csr_src[j];
        m = fmaxf(m, leaky(a_src[(size_t)s * 4 + head] + ad));
    }

    // pass 2: independent-iteration accumulate
    float denom = __expf(lself - m);
    __hip_bfloat162 hv0 = *(const __hip_bfloat162*)(h + (size_t)w * DMODEL + lane * 2);
    float2 acc;
    acc.x = __bfloat162float(hv0.x) * denom;
    acc.y = __bfloat162float(hv0.y) * denom;
    for (int j = j0; j < j1; j++) {
        int s = csr_src[j];
        float p = __expf(leaky(a_src[(size_t)s * 4 + head] + ad) - m);
        __hip_bfloat162 hv = *(const __hip_bfloat162*)(h + (size_t)s * DMODEL + lane * 2);
        acc.x += p * __bfloat162float(hv.x);
        acc.y += p * __bfloat162float(hv.y);
        denom += p;
    }

    float2 b = *(const float2*)(bias + lane * 2);
    float inv = 1.f / denom;
    float2 o;
    o.x = tanhf(acc.x * inv + b.x);
    o.y = tanhf(acc.y * inv + b.y);
    *(float2*)(out + (size_t)w * DMODEL + lane * 2) = o;
}

extern "C" void kernel_launch(void* const* d_in, const int* in_sizes, int n_in,
                              void* d_out, int out_size, void* d_ws, size_t ws_size,
                              hipStream_t stream) {
    const float* x       = (const float*)d_in[0];
    const int*   edges   = (const int*)d_in[1];   // [2,E]: row0=src, row1=dst
    const float* W       = (const float*)d_in[2];
    const float* att_src = (const float*)d_in[3];
    const float* att_dst = (const float*)d_in[4];
    const float* bias    = (const float*)d_in[5];
    float* out = (float*)d_out;

    const int N = in_sizes[0] / DMODEL;   // 50000
    const int E = in_sizes[1] / 2;        // 600000
    const int* srcs = edges;
    const int* dsts = edges + E;

    // workspace layout:
    // h[N*128] bf16 | a_src[N*4] f32 | a_dst[N*4] f32 | deg[N] i32 |
    // bsum[nb] i32 | offsets[N+1] i32 | cursor[N] i32 | csr_src[E] i32
    const int nb = (N + SCAN_CHUNK - 1) / SCAN_CHUNK;
    __hip_bfloat16* h = (__hip_bfloat16*)d_ws;
    float* a_src_d = (float*)((char*)d_ws + (size_t)N * DMODEL * sizeof(__hip_bfloat16));
    float* a_dst_d = a_src_d + (size_t)N * 4;
    int* deg     = (int*)(a_dst_d + (size_t)N * 4);
    int* bsum    = deg + N;
    int* offsets = bsum + nb;
    int* cursor  = offsets + (N + 1);
    int* csr_src = cursor + N;

    k1_gemm_att<<<(N + 7) / 8, 128, 0, stream>>>(x, W, att_src, att_dst,
                                                 h, a_src_d, a_dst_d, N);
    kz_zero<<<(N + 255) / 256, 256, 0, stream>>>(deg, N);
    kc_count<<<(E + 255) / 256, 256, 0, stream>>>(dsts, deg, E);
    ks1_bsum<<<nb, 256, 0, stream>>>(deg, bsum, N);
    ks2_scan<<<1, 64, 0, stream>>>(bsum, nb);
    ks3_scan<<<nb, 256, 0, stream>>>(deg, bsum, offsets, cursor, N, E);
    kf_fill<<<(E + 255) / 256, 256, 0, stream>>>(srcs, dsts, cursor, csr_src, E);
    kagg<<<(N * 64 + 255) / 256, 256, 0, stream>>>(offsets, csr_src, h, a_src_d,
                                                   a_dst_d, bias, out, N);
}

// Round 4
// 226.340 us; speedup vs baseline: 3.8522x; 1.2867x over previous
//
#include <hip/hip_runtime.h>
#include <hip/hip_bf16.h>
#include <math.h>

#define NEG_SLOPE 0.2f
#define DMODEL 128
#define SCAN_CHUNK 1024

typedef __attribute__((ext_vector_type(8))) short short8;
typedef __attribute__((ext_vector_type(4))) float floatx4;

__device__ __forceinline__ float leaky(float x) { return x >= 0.f ? x : NEG_SLOPE * x; }

// ---- convert x fp32 -> bf16 (vectorized) ----
__global__ __launch_bounds__(256) void kcx(const float* __restrict__ x,
                                           __hip_bfloat16* __restrict__ xbf, int total4) {
    int i = blockIdx.x * 256 + threadIdx.x;
    if (i >= total4) return;
    float4 v = ((const float4*)x)[i];
    __hip_bfloat16 o[4] = {__float2bfloat16(v.x), __float2bfloat16(v.y),
                           __float2bfloat16(v.z), __float2bfloat16(v.w)};
    *(short4*)(xbf + (size_t)i * 4) = *(const short4*)o;
}

// ---- convert W fp32 -> bf16, transposed: Wt[n][k] = W[k][n] ----
__global__ __launch_bounds__(256) void kcw(const float* __restrict__ W,
                                           __hip_bfloat16* __restrict__ Wt) {
    int idx = blockIdx.x * 256 + threadIdx.x;  // 16384 threads
    int n = idx >> 7, k = idx & 127;
    Wt[idx] = __float2bfloat16(W[k * DMODEL + n]);
}

// ---- K1M: h = x@W via MFMA. Block=256 (4 waves), wave = 16 nodes x 128 cols ----
__global__ __launch_bounds__(256) void k1m(const __hip_bfloat16* __restrict__ xbf,
                                           const __hip_bfloat16* __restrict__ Wt,
                                           __hip_bfloat16* __restrict__ h, int N) {
    const int wv = threadIdx.x >> 6, lane = threadIdx.x & 63;
    const int node0 = blockIdx.x * 64 + wv * 16;
    const int m = lane & 15, kq = lane >> 4;   // quad in [0,4)
    floatx4 acc[8];
    #pragma unroll
    for (int t = 0; t < 8; t++) acc[t] = (floatx4)(0.f);

    int arow = node0 + m; if (arow >= N) arow = N - 1;
    const short* ap = (const short*)xbf + (size_t)arow * DMODEL + kq * 8;
    const short* bp = (const short*)Wt + m * DMODEL + kq * 8;

    #pragma unroll
    for (int ks = 0; ks < 4; ks++) {            // K step = 32
        short8 a = *(const short8*)(ap + ks * 32);
        #pragma unroll
        for (int nt = 0; nt < 8; nt++) {
            short8 b = *(const short8*)(bp + nt * 16 * DMODEL + ks * 32);
            acc[nt] = __builtin_amdgcn_mfma_f32_16x16x32_bf16(a, b, acc[nt], 0, 0, 0);
        }
    }
    // C/D layout: col = lane&15 (=m), row = kq*4 + reg   [m89-verified]
    #pragma unroll
    for (int nt = 0; nt < 8; nt++) {
        #pragma unroll
        for (int r = 0; r < 4; r++) {
            int node = node0 + kq * 4 + r;
            if (node < N)
                h[(size_t)node * DMODEL + nt * 16 + m] = __float2bfloat16(acc[nt][r]);
        }
    }
}

// ---- KA: per-node attention halves from h (2 nodes / 256-thread block) ----
__global__ __launch_bounds__(256) void ka(const __hip_bfloat16* __restrict__ h,
                                          const float* __restrict__ att_src,
                                          const float* __restrict__ att_dst,
                                          float* __restrict__ a_src,
                                          float* __restrict__ a_dst, int N) {
    const int t = threadIdx.x;
    const int n = blockIdx.x * 2 + (t >> 7);
    const int c = t & 127;
    if (n >= N) return;
    float hv = __bfloat162float(h[(size_t)n * DMODEL + c]);
    float vs = hv * att_src[c];
    float vd = hv * att_dst[c];
    #pragma unroll
    for (int off = 16; off > 0; off >>= 1) {
        vs += __shfl_xor(vs, off, 32);
        vd += __shfl_xor(vd, off, 32);
    }
    if ((c & 31) == 0) {
        a_src[n * 4 + (c >> 5)] = vs;
        a_dst[n * 4 + (c >> 5)] = vd;
    }
}

// ---- CSR build ----
__global__ __launch_bounds__(256) void kz_zero(int* __restrict__ deg, int N) {
    int i = blockIdx.x * 256 + threadIdx.x;
    if (i < N) deg[i] = 0;
}
__global__ __launch_bounds__(256) void kc_count(const int* __restrict__ dsts,
                                                int* __restrict__ deg, int E) {
    int e = blockIdx.x * 256 + threadIdx.x;
    if (e < E) atomicAdd(&deg[dsts[e]], 1);
}
__global__ __launch_bounds__(256) void ks1_bsum(const int* __restrict__ deg,
                                                int* __restrict__ bsum, int N) {
    const int t = threadIdx.x, lane = t & 63, wv = t >> 6;
    int base = blockIdx.x * SCAN_CHUNK + t * 4;
    int s = 0;
    #pragma unroll
    for (int j = 0; j < 4; j++) { int i = base + j; if (i < N) s += deg[i]; }
    #pragma unroll
    for (int off = 32; off > 0; off >>= 1) s += __shfl_xor(s, off, 64);
    __shared__ int ws[4];
    if (lane == 0) ws[wv] = s;
    __syncthreads();
    if (t == 0) bsum[blockIdx.x] = ws[0] + ws[1] + ws[2] + ws[3];
}
__global__ __launch_bounds__(64) void ks2_scan(int* __restrict__ bsum, int nb) {
    const int lane = threadIdx.x;
    int run = 0;
    for (int base = 0; base < nb; base += 64) {
        int i = base + lane;
        int v = (i < nb) ? bsum[i] : 0;
        int xx = v;
        #pragma unroll
        for (int off = 1; off < 64; off <<= 1) {
            int y = __shfl_up(xx, off, 64);
            if (lane >= off) xx += y;
        }
        if (i < nb) bsum[i] = run + xx - v;
        run += __shfl(xx, 63, 64);
    }
}
__global__ __launch_bounds__(256) void ks3_scan(const int* __restrict__ deg,
                                                const int* __restrict__ bsum,
                                                int* __restrict__ offsets,
                                                int* __restrict__ cursor, int N, int E) {
    const int t = threadIdx.x, lane = t & 63, wv = t >> 6;
    int base = blockIdx.x * SCAN_CHUNK + t * 4;
    int v[4]; int s = 0;
    #pragma unroll
    for (int j = 0; j < 4; j++) { int i = base + j; v[j] = (i < N) ? deg[i] : 0; s += v[j]; }
    int xinc = s;
    #pragma unroll
    for (int off = 1; off < 64; off <<= 1) {
        int y = __shfl_up(xinc, off, 64);
        if (lane >= off) xinc += y;
    }
    __shared__ int ws[4];
    if (lane == 63) ws[wv] = xinc;
    __syncthreads();
    int woff = 0;
    #pragma unroll
    for (int j = 0; j < 4; j++) if (j < wv) woff += ws[j];
    int run = bsum[blockIdx.x] + woff + xinc - s;
    #pragma unroll
    for (int j = 0; j < 4; j++) {
        int i = base + j;
        if (i < N) { offsets[i] = run; cursor[i] = run; }
        run += v[j];
    }
    if (blockIdx.x == 0 && t == 0) offsets[N] = E;
}
__global__ __launch_bounds__(256) void kf_fill(const int* __restrict__ srcs,
                                               const int* __restrict__ dsts,
                                               int* __restrict__ cursor,
                                               int* __restrict__ csr_src, int E) {
    int e = blockIdx.x * 256 + threadIdx.x;
    if (e < E) {
        int pos = atomicAdd(&cursor[dsts[e]], 1);
        csr_src[pos] = srcs[e];
    }
}

// ---- KAGG: one wave per dst node — single-pass (shift by self logit), ----
// ---- lane-prefetched edge ids + 2x unrolled independent gathers.       ----
__global__ __launch_bounds__(256) void kagg(
    const int* __restrict__ offsets, const int* __restrict__ csr_src,
    const __hip_bfloat16* __restrict__ h, const float* __restrict__ a_src,
    const float* __restrict__ a_dst, const float* __restrict__ bias,
    float* __restrict__ out, int N)
{
    int w = (blockIdx.x * 256 + threadIdx.x) >> 6;  // wave id = dst node
    if (w >= N) return;
    const int lane = threadIdx.x & 63;
    const int head = lane >> 4;

    const float ad = a_dst[(size_t)w * 4 + head];
    const float lself = leaky(a_src[(size_t)w * 4 + head] + ad);

    float denom = 1.f;  // exp(lself - lself)
    __hip_bfloat162 hs = *(const __hip_bfloat162*)(h + (size_t)w * DMODEL + lane * 2);
    float2 acc = {__bfloat162float(hs.x), __bfloat162float(hs.y)};

    const int j0 = offsets[w], j1 = offsets[w + 1];
    for (int base = j0; base < j1; base += 64) {
        int cnt = j1 - base; if (cnt > 64) cnt = 64;
        int sv = (base + lane < j1) ? csr_src[base + lane] : 0;  // coalesced prefetch
        int jj = 0;
        for (; jj + 2 <= cnt; jj += 2) {
            int s0 = __builtin_amdgcn_readlane(sv, jj);
            int s1 = __builtin_amdgcn_readlane(sv, jj + 1);
            float as0 = a_src[(size_t)s0 * 4 + head];
            float as1 = a_src[(size_t)s1 * 4 + head];
            __hip_bfloat162 h0 = *(const __hip_bfloat162*)(h + (size_t)s0 * DMODEL + lane * 2);
            __hip_bfloat162 h1 = *(const __hip_bfloat162*)(h + (size_t)s1 * DMODEL + lane * 2);
            float p0 = __expf(leaky(as0 + ad) - lself);
            float p1 = __expf(leaky(as1 + ad) - lself);
            acc.x += p0 * __bfloat162float(h0.x) + p1 * __bfloat162float(h1.x);
            acc.y += p0 * __bfloat162float(h0.y) + p1 * __bfloat162float(h1.y);
            denom += p0 + p1;
        }
        if (jj < cnt) {
            int s0 = __builtin_amdgcn_readlane(sv, jj);
            float as0 = a_src[(size_t)s0 * 4 + head];
            __hip_bfloat162 h0 = *(const __hip_bfloat162*)(h + (size_t)s0 * DMODEL + lane * 2);
            float p0 = __expf(leaky(as0 + ad) - lself);
            acc.x += p0 * __bfloat162float(h0.x);
            acc.y += p0 * __bfloat162float(h0.y);
            denom += p0;
        }
    }
    float2 b = *(const float2*)(bias + lane * 2);
    float inv = 1.f / denom;
    float2 o;
    o.x = tanhf(acc.x * inv + b.x);
    o.y = tanhf(acc.y * inv + b.y);
    *(float2*)(out + (size_t)w * DMODEL + lane * 2) = o;
}

extern "C" void kernel_launch(void* const* d_in, const int* in_sizes, int n_in,
                              void* d_out, int out_size, void* d_ws, size_t ws_size,
                              hipStream_t stream) {
    const float* x       = (const float*)d_in[0];
    const int*   edges   = (const int*)d_in[1];   // [2,E]: row0=src, row1=dst
    const float* W       = (const float*)d_in[2];
    const float* att_src = (const float*)d_in[3];
    const float* att_dst = (const float*)d_in[4];
    const float* bias    = (const float*)d_in[5];
    float* out = (float*)d_out;

    const int N = in_sizes[0] / DMODEL;   // 50000
    const int E = in_sizes[1] / 2;        // 600000
    const int* srcs = edges;
    const int* dsts = edges + E;

    // ws layout: xbf[N*128]bf16 | Wt[128*128]bf16 | h[N*128]bf16 |
    //            a_src[N*4]f32 | a_dst[N*4]f32 | deg[N] | bsum[nb] |
    //            offsets[N+1] | cursor[N] | csr_src[E]
    const int nb = (N + SCAN_CHUNK - 1) / SCAN_CHUNK;
    __hip_bfloat16* xbf = (__hip_bfloat16*)d_ws;
    __hip_bfloat16* Wt  = xbf + (size_t)N * DMODEL;
    __hip_bfloat16* h   = Wt + DMODEL * DMODEL;
    float* a_src_d = (float*)(h + (size_t)N * DMODEL);
    float* a_dst_d = a_src_d + (size_t)N * 4;
    int* deg     = (int*)(a_dst_d + (size_t)N * 4);
    int* bsum    = deg + N;
    int* offsets = bsum + nb;
    int* cursor  = offsets + (N + 1);
    int* csr_src = cursor + N;

    const int total4 = N * DMODEL / 4;
    kcx<<<(total4 + 255) / 256, 256, 0, stream>>>(x, xbf, total4);
    kcw<<<(DMODEL * DMODEL + 255) / 256, 256, 0, stream>>>(W, Wt);
    k1m<<<(N + 63) / 64, 256, 0, stream>>>(xbf, Wt, h, N);
    ka<<<(N + 1) / 2, 256, 0, stream>>>(h, att_src, att_dst, a_src_d, a_dst_d, N);
    kz_zero<<<(N + 255) / 256, 256, 0, stream>>>(deg, N);
    kc_count<<<(E + 255) / 256, 256, 0, stream>>>(dsts, deg, E);
    ks1_bsum<<<nb, 256, 0, stream>>>(deg, bsum, N);
    ks2_scan<<<1, 64, 0, stream>>>(bsum, nb);
    ks3_scan<<<nb, 256, 0, stream>>>(deg, bsum, offsets, cursor, N, E);
    kf_fill<<<(E + 255) / 256, 256, 0, stream>>>(srcs, dsts, cursor, csr_src, E);
    kagg<<<((size_t)N * 64 + 255) / 256, 256, 0, stream>>>(offsets, csr_src, h, a_src_d,
                                                           a_dst_d, bias, out, N);
}